// Round 1
// baseline (358.201 us; speedup 1.0000x reference)
//
#include <hip/hip_runtime.h>

typedef unsigned short ushort_t;
typedef __attribute__((ext_vector_type(8))) __bf16 bf16x8;
typedef __attribute__((ext_vector_type(4))) float f32x4;
typedef __attribute__((ext_vector_type(8))) unsigned short ushort8;

constexpr int S = 2048;
constexpr int D = 2048;
constexpr int NQKV = 3072;       // (32 + 2*8) * 64
constexpr int NH = 32, DH = 64;

static __device__ __forceinline__ float bf2f(ushort_t u) {
    return __uint_as_float(((unsigned int)u) << 16);
}
static __device__ __forceinline__ ushort_t f2bf(float f) {
    unsigned int u = __float_as_uint(f);
    u = (u + 0x7fffu + ((u >> 16) & 1u)) >> 16;   // round-to-nearest-even
    return (ushort_t)u;
}

// ---------- fp32 -> bf16 straight copy ----------
__global__ void k_cvt(const float* __restrict__ src, ushort_t* __restrict__ dst, int n4) {
    int i = blockIdx.x * blockDim.x + threadIdx.x;
    if (i < n4) {
        float4 v = ((const float4*)src)[i];
        ushort4 o;
        o.x = f2bf(v.x); o.y = f2bf(v.y); o.z = f2bf(v.z); o.w = f2bf(v.w);
        ((ushort4*)dst)[i] = o;
    }
}

// ---------- fp32 [R][C] -> bf16 [C][R] (transpose + convert) ----------
__global__ void k_transpose_cvt(const float* __restrict__ src, ushort_t* __restrict__ dst,
                                int R, int C) {
    __shared__ float tile[32][33];
    int c0 = blockIdx.x * 32, r0 = blockIdx.y * 32;
    int tx = threadIdx.x, ty = threadIdx.y;   // 32 x 8
#pragma unroll
    for (int j = 0; j < 32; j += 8)
        tile[ty + j][tx] = src[(size_t)(r0 + ty + j) * C + c0 + tx];
    __syncthreads();
#pragma unroll
    for (int j = 0; j < 32; j += 8)
        dst[(size_t)(c0 + ty + j) * R + r0 + tx] = f2bf(tile[tx][ty + j]);
}

// ---------- bf16 GEMM: C[M][N] = A[M][K] @ BT[N][K]^T + bias ----------
template <bool OUT_F32>
__global__ __launch_bounds__(256) void k_gemm(
    const ushort_t* __restrict__ A,   // [M][K] bf16
    const ushort_t* __restrict__ BT,  // [N][K] bf16
    const float* __restrict__ bias,   // [N]
    void* __restrict__ Cout,          // [M][N] f32 or bf16
    int M, int N, int K)
{
    constexpr int BK = 32;
    __shared__ ushort_t As[128][BK + 8];
    __shared__ ushort_t Bs[128][BK + 8];
    const int m0 = blockIdx.y * 128;
    const int n0 = blockIdx.x * 128;
    const int t = threadIdx.x;
    const int lane = t & 63, wid = t >> 6;
    const int wm = (wid >> 1) * 64, wn = (wid & 1) * 64;
    const int lr = lane & 15, kg = (lane >> 4) * 8;

    f32x4 acc[4][4] = {};

    for (int k0 = 0; k0 < K; k0 += BK) {
#pragma unroll
        for (int i = 0; i < 2; ++i) {
            int id = t + i * 256;
            int r = id >> 2, kc = (id & 3) * 8;
            *(ushort8*)&As[r][kc] = *(const ushort8*)&A[(size_t)(m0 + r) * K + k0 + kc];
            *(ushort8*)&Bs[r][kc] = *(const ushort8*)&BT[(size_t)(n0 + r) * K + k0 + kc];
        }
        __syncthreads();
        bf16x8 af[4], bfr[4];
#pragma unroll
        for (int i = 0; i < 4; ++i) {
            af[i]  = *(const bf16x8*)&As[wm + i * 16 + lr][kg];
            bfr[i] = *(const bf16x8*)&Bs[wn + i * 16 + lr][kg];
        }
#pragma unroll
        for (int i = 0; i < 4; ++i)
#pragma unroll
            for (int j = 0; j < 4; ++j)
                acc[i][j] = __builtin_amdgcn_mfma_f32_16x16x32_bf16(af[i], bfr[j], acc[i][j], 0, 0, 0);
        __syncthreads();
    }

    const int lg = (lane >> 4) * 4;
#pragma unroll
    for (int j = 0; j < 4; ++j) {
        int n = n0 + wn + j * 16 + lr;
        float bv = bias[n];
#pragma unroll
        for (int i = 0; i < 4; ++i) {
#pragma unroll
            for (int r = 0; r < 4; ++r) {
                int m = m0 + wm + i * 16 + lg + r;
                float v = acc[i][j][r] + bv;
                if constexpr (OUT_F32) ((float*)Cout)[(size_t)m * N + n] = v;
                else ((ushort_t*)Cout)[(size_t)m * N + n] = f2bf(v);
            }
        }
    }
}

// ---------- RoPE in-place on bf16 qkv (q heads 0..31, k heads 32..39) ----------
__global__ void k_rope(ushort_t* qkv) {
    int idx = blockIdx.x * blockDim.x + threadIdx.x;   // S*40*16 threads
    int i = idx & 15;
    int sh = idx >> 4;
    int h = sh % 40;
    int s = sh / 40;
    if (s >= S) return;
    int col = (h < 32) ? h * 64 : 2048 + (h - 32) * 64;
    ushort_t* p = qkv + (size_t)s * NQKV + col;
    float x1 = bf2f(p[i]), x2 = bf2f(p[i + 16]);
    // inv_freq = 10000^(-i/16) = exp2(-i * log2(10000)/16)
    float inv = exp2f(-(float)i * 0.83048202372f);
    float f = (float)s * inv;
    float c, sn;
    sincosf(f, &sn, &c);
    p[i]      = f2bf(x1 * c - x2 * sn);
    p[i + 16] = f2bf(x1 * sn + x2 * c);
}

// ---------- flash-style causal GQA attention ----------
// grid: (NH, S/64). block: 256 threads (4 waves, each wave owns 16 q rows).
__global__ __launch_bounds__(256) void k_attn(const ushort_t* __restrict__ qkv,
                                              ushort_t* __restrict__ out) {
    constexpr int KB = 32;
    __shared__ ushort_t Ks[KB][DH + 8];       // [kv][dh]
    __shared__ ushort_t Vs[DH][KB + 8];       // [dh][kv] (transposed)
    __shared__ ushort_t Ps[4][16][KB + 8];    // per-wave P tile

    const int h = blockIdx.x;
    const int q0 = blockIdx.y * 64;
    const int kvh = h >> 2;                   // GQA group of 4
    const int t = threadIdx.x, lane = t & 63, w = t >> 6;
    const int lr = lane & 15, kg = (lane >> 4) * 8;
    const int rbase = (lane >> 4) * 4;
    const int qw = q0 + w * 16;

    // Q fragments (2 k-slices of 32), straight from global
    bf16x8 qf0, qf1;
    {
        const ushort_t* qp = qkv + (size_t)(qw + lr) * NQKV + h * DH;
        qf0 = *(const bf16x8*)&qp[kg];
        qf1 = *(const bf16x8*)&qp[32 + kg];
    }

    float mrun[4] = {-1e30f, -1e30f, -1e30f, -1e30f};
    float lrun[4] = {0.f, 0.f, 0.f, 0.f};
    f32x4 o[4] = {};                          // 4 col-tiles of 16

    const int ntile = (q0 + 64) / KB;
    for (int kt = 0; kt < ntile; ++kt) {
        const int kv0 = kt * KB;
        {   // stage K ([kv][dh]) and V transposed ([dh][kv])
            int r = t >> 3, dc = (t & 7) * 8;
            *(ushort8*)&Ks[r][dc] =
                *(const ushort8*)&qkv[(size_t)(kv0 + r) * NQKV + 2048 + kvh * DH + dc];
            ushort8 v = *(const ushort8*)&qkv[(size_t)(kv0 + r) * NQKV + 2560 + kvh * DH + dc];
#pragma unroll
            for (int e = 0; e < 8; ++e) Vs[dc + e][r] = v[e];
        }
        __syncthreads();

        // S = Q K^T  (16 q-rows x 32 kv)
        f32x4 s0 = {}, s1 = {};
        {
            bf16x8 b00 = *(const bf16x8*)&Ks[lr][kg];
            bf16x8 b01 = *(const bf16x8*)&Ks[lr][32 + kg];
            bf16x8 b10 = *(const bf16x8*)&Ks[16 + lr][kg];
            bf16x8 b11 = *(const bf16x8*)&Ks[16 + lr][32 + kg];
            s0 = __builtin_amdgcn_mfma_f32_16x16x32_bf16(qf0, b00, s0, 0, 0, 0);
            s0 = __builtin_amdgcn_mfma_f32_16x16x32_bf16(qf1, b01, s0, 0, 0, 0);
            s1 = __builtin_amdgcn_mfma_f32_16x16x32_bf16(qf0, b10, s1, 0, 0, 0);
            s1 = __builtin_amdgcn_mfma_f32_16x16x32_bf16(qf1, b11, s1, 0, 0, 0);
        }

        // scale + causal mask + online softmax
#pragma unroll
        for (int r = 0; r < 4; ++r) {
            int qrow = qw + rbase + r;
            float v0 = s0[r] * 0.125f, v1 = s1[r] * 0.125f;
            if (kv0 + lr > qrow)      v0 = -1e30f;
            if (kv0 + 16 + lr > qrow) v1 = -1e30f;

            float m = fmaxf(v0, v1);
            m = fmaxf(m, __shfl_xor(m, 1));
            m = fmaxf(m, __shfl_xor(m, 2));
            m = fmaxf(m, __shfl_xor(m, 4));
            m = fmaxf(m, __shfl_xor(m, 8));

            float mn = fmaxf(mrun[r], m);
            float alpha = __expf(mrun[r] - mn);
            float p0 = __expf(v0 - mn);
            float p1 = __expf(v1 - mn);
            float sum = p0 + p1;
            sum += __shfl_xor(sum, 1);
            sum += __shfl_xor(sum, 2);
            sum += __shfl_xor(sum, 4);
            sum += __shfl_xor(sum, 8);
            lrun[r] = lrun[r] * alpha + sum;
            mrun[r] = mn;
            o[0][r] *= alpha; o[1][r] *= alpha; o[2][r] *= alpha; o[3][r] *= alpha;

            Ps[w][rbase + r][lr]      = f2bf(p0);
            Ps[w][rbase + r][16 + lr] = f2bf(p1);
        }

        // O += P @ V
        {
            bf16x8 pa = *(const bf16x8*)&Ps[w][lr][kg];
#pragma unroll
            for (int tt = 0; tt < 4; ++tt) {
                bf16x8 vb = *(const bf16x8*)&Vs[tt * 16 + lr][kg];
                o[tt] = __builtin_amdgcn_mfma_f32_16x16x32_bf16(pa, vb, o[tt], 0, 0, 0);
            }
        }
        __syncthreads();
    }

    // epilogue: O / l, write bf16
#pragma unroll
    for (int tt = 0; tt < 4; ++tt) {
#pragma unroll
        for (int r = 0; r < 4; ++r) {
            int qrow = qw + rbase + r;
            out[(size_t)qrow * D + h * DH + tt * 16 + lr] = f2bf(o[tt][r] / lrun[r]);
        }
    }
}

extern "C" void kernel_launch(void* const* d_in, const int* in_sizes, int n_in,
                              void* d_out, int out_size, void* d_ws, size_t ws_size,
                              hipStream_t stream) {
    const float* x    = (const float*)d_in[0];
    const float* Wqkv = (const float*)d_in[1];
    const float* bqkv = (const float*)d_in[2];
    const float* Wout = (const float*)d_in[3];
    const float* bout = (const float*)d_in[4];
    float* out = (float*)d_out;

    char* ws = (char*)d_ws;
    ushort_t* xb    = (ushort_t*)(ws);                       //  8 MB  x bf16
    ushort_t* wqkvT = (ushort_t*)(ws + (8u  << 20));         // 12 MB  Wqkv^T bf16 [3072][2048]
    ushort_t* woutT = (ushort_t*)(ws + (20u << 20));         //  8 MB  Wout^T bf16 [2048][2048]
    ushort_t* qkvb  = (ushort_t*)(ws + (28u << 20));         // 12 MB  qkv bf16 [2048][3072]
    ushort_t* ao    = (ushort_t*)(ws + (40u << 20));         //  8 MB  attn out bf16 [2048][2048]

    k_cvt<<<(S * D / 4 + 255) / 256, 256, 0, stream>>>(x, xb, S * D / 4);
    k_transpose_cvt<<<dim3(NQKV / 32, D / 32), dim3(32, 8), 0, stream>>>(Wqkv, wqkvT, D, NQKV);
    k_transpose_cvt<<<dim3(D / 32, D / 32), dim3(32, 8), 0, stream>>>(Wout, woutT, D, D);
    k_gemm<false><<<dim3(NQKV / 128, S / 128), 256, 0, stream>>>(xb, wqkvT, bqkv, qkvb, S, NQKV, D);
    k_rope<<<(S * 40 * 16) / 256, 256, 0, stream>>>(qkvb);
    k_attn<<<dim3(NH, S / 64), 256, 0, stream>>>(qkvb, ao);
    k_gemm<true><<<dim3(D / 128, S / 128), 256, 0, stream>>>(ao, woutT, bout, out, S, D, D);
}

// Round 5
// 290.612 us; speedup vs baseline: 1.2326x; 1.2326x over previous
//
#include <hip/hip_runtime.h>

typedef unsigned short ushort_t;
typedef __attribute__((ext_vector_type(8))) __bf16 bf16x8;
typedef __attribute__((ext_vector_type(4))) float f32x4;
typedef __attribute__((ext_vector_type(8))) unsigned short ushort8;
typedef __attribute__((ext_vector_type(4))) int int4v;

constexpr int S = 2048;
constexpr int D = 2048;
constexpr int NQKV = 3072;       // (32 + 2*8) * 64
constexpr int NH = 32, DH = 64;

static __device__ __forceinline__ float bf2f(ushort_t u) {
    return __uint_as_float(((unsigned int)u) << 16);
}
static __device__ __forceinline__ ushort_t f2bf(float f) {
    unsigned int u = __float_as_uint(f);
    u = (u + 0x7fffu + ((u >> 16) & 1u)) >> 16;   // round-to-nearest-even
    return (ushort_t)u;
}

// ---------- fp32 -> bf16 straight copy ----------
__global__ void k_cvt(const float* __restrict__ src, ushort_t* __restrict__ dst, int n4) {
    int i = blockIdx.x * blockDim.x + threadIdx.x;
    if (i < n4) {
        float4 v = ((const float4*)src)[i];
        ushort4 o;
        o.x = f2bf(v.x); o.y = f2bf(v.y); o.z = f2bf(v.z); o.w = f2bf(v.w);
        ((ushort4*)dst)[i] = o;
    }
}

// ---------- fp32 [R][C] -> bf16 [C][R] (transpose + convert) ----------
__global__ void k_transpose_cvt(const float* __restrict__ src, ushort_t* __restrict__ dst,
                                int R, int C) {
    __shared__ float tile[32][33];
    int c0 = blockIdx.x * 32, r0 = blockIdx.y * 32;
    int tx = threadIdx.x, ty = threadIdx.y;   // 32 x 8
#pragma unroll
    for (int j = 0; j < 32; j += 8)
        tile[ty + j][tx] = src[(size_t)(r0 + ty + j) * C + c0 + tx];
    __syncthreads();
#pragma unroll
    for (int j = 0; j < 32; j += 8)
        dst[(size_t)(c0 + ty + j) * R + r0 + tx] = f2bf(tile[tx][ty + j]);
}

// ---------- bf16 GEMM (round-1 verified reg-staged): C = A @ BT^T + bias ----------
template <bool OUT_F32>
__global__ __launch_bounds__(256) void k_gemm(
    const ushort_t* __restrict__ A,   // [M][K] bf16
    const ushort_t* __restrict__ BT,  // [N][K] bf16
    const float* __restrict__ bias,   // [N]
    void* __restrict__ Cout,          // [M][N] f32 or bf16
    int M, int N, int K)
{
    constexpr int BK = 32;
    __shared__ ushort_t As[128][BK + 8];
    __shared__ ushort_t Bs[128][BK + 8];
    const int m0 = blockIdx.y * 128;
    const int n0 = blockIdx.x * 128;
    const int t = threadIdx.x;
    const int lane = t & 63, wid = t >> 6;
    const int wm = (wid >> 1) * 64, wn = (wid & 1) * 64;
    const int lr = lane & 15, kg = (lane >> 4) * 8;

    f32x4 acc[4][4] = {};

    for (int k0 = 0; k0 < K; k0 += BK) {
#pragma unroll
        for (int i = 0; i < 2; ++i) {
            int id = t + i * 256;
            int r = id >> 2, kc = (id & 3) * 8;
            *(ushort8*)&As[r][kc] = *(const ushort8*)&A[(size_t)(m0 + r) * K + k0 + kc];
            *(ushort8*)&Bs[r][kc] = *(const ushort8*)&BT[(size_t)(n0 + r) * K + k0 + kc];
        }
        __syncthreads();
        bf16x8 af[4], bfr[4];
#pragma unroll
        for (int i = 0; i < 4; ++i) {
            af[i]  = *(const bf16x8*)&As[wm + i * 16 + lr][kg];
            bfr[i] = *(const bf16x8*)&Bs[wn + i * 16 + lr][kg];
        }
#pragma unroll
        for (int i = 0; i < 4; ++i)
#pragma unroll
            for (int j = 0; j < 4; ++j)
                acc[i][j] = __builtin_amdgcn_mfma_f32_16x16x32_bf16(af[i], bfr[j], acc[i][j], 0, 0, 0);
        __syncthreads();
    }

    const int lg = (lane >> 4) * 4;
#pragma unroll
    for (int j = 0; j < 4; ++j) {
        int n = n0 + wn + j * 16 + lr;
        float bv = bias[n];
#pragma unroll
        for (int i = 0; i < 4; ++i) {
#pragma unroll
            for (int r = 0; r < 4; ++r) {
                int m = m0 + wm + i * 16 + lg + r;
                float v = acc[i][j][r] + bv;
                if constexpr (OUT_F32) ((float*)Cout)[(size_t)m * N + n] = v;
                else ((ushort_t*)Cout)[(size_t)m * N + n] = f2bf(v);
            }
        }
    }
}

// ---------- RoPE in-place on bf16 qkv (q heads 0..31, k heads 32..39) ----------
__global__ void k_rope(ushort_t* qkv) {
    int idx = blockIdx.x * blockDim.x + threadIdx.x;   // S*40*16 threads
    int i = idx & 15;
    int sh = idx >> 4;
    int h = sh % 40;
    int s = sh / 40;
    if (s >= S) return;
    int col = (h < 32) ? h * 64 : 2048 + (h - 32) * 64;
    ushort_t* p = qkv + (size_t)s * NQKV + col;
    float x1 = bf2f(p[i]), x2 = bf2f(p[i + 16]);
    float inv = exp2f(-(float)i * 0.83048202372f);   // 10000^(-i/16)
    float f = (float)s * inv;
    float c, sn;
    sincosf(f, &sn, &c);
    p[i]      = f2bf(x1 * c - x2 * sn);
    p[i + 16] = f2bf(x1 * sn + x2 * c);
}

// ---------- flash-style causal GQA attention, swapped-operand S^T form ----------
// grid: (NH, 16). block: 512 threads = 8 waves, each wave owns 16 q rows (128/block).
// S^T = K*Q^T so each lane holds kv-slices for ONE q row: softmax = in-lane
// reduce + shfl_xor(16,32). P^T redistributed to PV B-frags via ds_bpermute.
// KEY: bpermute's register operand must be lane-invariant -> fetch both nt
// candidates (compile-time indices) and select by g>>1.
__global__ __launch_bounds__(512) void k_attn(const ushort_t* __restrict__ qkv,
                                              ushort_t* __restrict__ out) {
    __shared__ ushort_t Ks[64 * 72];   // [kv][dh], stride 72 halfwords
    __shared__ ushort_t Vs[64 * 64];   // V^T swizzled: (dh,kv) at dh*64 + (kv ^ (dh&56))

    const int h = blockIdx.x;
    const int by = blockIdx.y;
    const int qb = (by & 1) ? (15 - (by >> 1)) : (by >> 1);   // causal load balance
    const int q0 = qb * 128;
    const int kvh = h >> 2;           // GQA group of 4
    const int t = threadIdx.x, lane = t & 63, w = t >> 6;
    const int lr = lane & 15, g = lane >> 4;
    const int qw = q0 + w * 16;
    const int qg = qw + lr;           // this lane's q row

    // Q as B-frag: lane holds Q[q=lr][d = g*8 + 32s + j]
    bf16x8 qf0, qf1;
    {
        const ushort_t* qp = qkv + (size_t)qg * NQKV + h * DH + g * 8;
        qf0 = *(const bf16x8*)&qp[0];
        qf1 = *(const bf16x8*)&qp[32];
    }
    // bpermute source-lane byte indices: source lane = 16*g_src + lr,
    // g_src0 = 2*(g&1) (serves j=0..3), g_src1 = 2*(g&1)+1 (serves j=4..7)
    const int idx0 = (lr + 16 * (2 * (g & 1))) << 2;
    const int idx1 = (lr + 16 * (2 * (g & 1) + 1)) << 2;
    const bool hi = (g >> 1) != 0;

    float mrun = -1e30f, lrun = 0.f;
    f32x4 o[4] = {};                  // O^T: dh = 16tt + 4g + reg, q = lr

    const int sr = t >> 3, sc = (t & 7) * 8;  // staging: row 0..63, col 0..56
    const ushort_t* gK = qkv + (size_t)sr * NQKV + 2048 + kvh * DH + sc;
    const ushort_t* gV = qkv + (size_t)sr * NQKV + 2560 + kvh * DH + sc;

    const int ntile = (q0 + 128) / 64;
    for (int kt = 0; kt < ntile; ++kt) {
        const int kv0 = kt * 64;
        {
            ushort8 kk = *(const ushort8*)&gK[(size_t)kv0 * NQKV];
            *(ushort8*)&Ks[sr * 72 + sc] = kk;
            ushort8 vv = *(const ushort8*)&gV[(size_t)kv0 * NQKV];
#pragma unroll
            for (int e = 0; e < 8; ++e) Vs[(sc + e) * 64 + (sr ^ sc)] = vv[e];
        }
        __syncthreads();
        if (kv0 <= qw) {              // wave has visible kv in this tile
            // S^T tile: A = K rows (contig), B = Q^T (from regs)
            f32x4 s[4];
#pragma unroll
            for (int nt = 0; nt < 4; ++nt) {
                bf16x8 a0 = *(const bf16x8*)&Ks[(nt * 16 + lr) * 72 + g * 8];
                bf16x8 a1 = *(const bf16x8*)&Ks[(nt * 16 + lr) * 72 + 32 + g * 8];
                f32x4 a = {};
                a = __builtin_amdgcn_mfma_f32_16x16x32_bf16(a0, qf0, a, 0, 0, 0);
                a = __builtin_amdgcn_mfma_f32_16x16x32_bf16(a1, qf1, a, 0, 0, 0);
                s[nt] = a;
            }
            // scale + causal mask + online softmax (lane holds S^T[16nt+4g+r][lr])
            float tmax = -3e38f;
#pragma unroll
            for (int nt = 0; nt < 4; ++nt)
#pragma unroll
                for (int r = 0; r < 4; ++r) {
                    float v = s[nt][r] * 0.125f;
                    int kvg = kv0 + nt * 16 + 4 * g + r;
                    v = (kvg > qg) ? -1e30f : v;
                    s[nt][r] = v;
                    tmax = fmaxf(tmax, v);
                }
            tmax = fmaxf(tmax, __shfl_xor(tmax, 16));
            tmax = fmaxf(tmax, __shfl_xor(tmax, 32));
            float mn = fmaxf(mrun, tmax);
            float alpha = __expf(mrun - mn);
            float sum = 0.f;
#pragma unroll
            for (int nt = 0; nt < 4; ++nt)
#pragma unroll
                for (int r = 0; r < 4; ++r) {
                    float p = __expf(s[nt][r] - mn);
                    s[nt][r] = p;
                    sum += p;
                }
            sum += __shfl_xor(sum, 16);
            sum += __shfl_xor(sum, 32);
            lrun = lrun * alpha + sum;
            mrun = mn;
#pragma unroll
            for (int tt = 0; tt < 4; ++tt) o[tt] *= alpha;

            // pack P^T to bf16 pairs: pk[nt*2+rp] = (r=2rp, r=2rp+1) of tile nt
            int pk[8];
#pragma unroll
            for (int nt = 0; nt < 4; ++nt)
#pragma unroll
                for (int rp = 0; rp < 2; ++rp) {
                    int dd;
                    asm("v_cvt_pk_bf16_f32 %0, %1, %2"
                        : "=v"(dd) : "v"(s[nt][2 * rp]), "v"(s[nt][2 * rp + 1]));
                    pk[nt * 2 + rp] = dd;
                }
            // redistribute to B-frag (kv = 32ks + 8g + j, q = lr) and PV.
            // dest needs nt = 2ks + (g>>1); register index must be lane-invariant,
            // so bpermute both candidates and cndmask-select.
#pragma unroll
            for (int ks = 0; ks < 2; ++ks) {
                int a0 = __builtin_amdgcn_ds_bpermute(idx0, pk[(2 * ks) * 2 + 0]);
                int b0 = __builtin_amdgcn_ds_bpermute(idx0, pk[(2 * ks + 1) * 2 + 0]);
                int a1 = __builtin_amdgcn_ds_bpermute(idx0, pk[(2 * ks) * 2 + 1]);
                int b1 = __builtin_amdgcn_ds_bpermute(idx0, pk[(2 * ks + 1) * 2 + 1]);
                int a2 = __builtin_amdgcn_ds_bpermute(idx1, pk[(2 * ks) * 2 + 0]);
                int b2 = __builtin_amdgcn_ds_bpermute(idx1, pk[(2 * ks + 1) * 2 + 0]);
                int a3 = __builtin_amdgcn_ds_bpermute(idx1, pk[(2 * ks) * 2 + 1]);
                int b3 = __builtin_amdgcn_ds_bpermute(idx1, pk[(2 * ks + 1) * 2 + 1]);
                int4v pb;
                pb.x = hi ? b0 : a0;   // j=0,1
                pb.y = hi ? b1 : a1;   // j=2,3
                pb.z = hi ? b2 : a2;   // j=4,5
                pb.w = hi ? b3 : a3;   // j=6,7
                bf16x8 pf = __builtin_bit_cast(bf16x8, pb);
#pragma unroll
                for (int tt = 0; tt < 4; ++tt) {
                    const int dh = tt * 16 + lr;
                    bf16x8 va = *(const bf16x8*)&Vs[dh * 64 + ((32 * ks + g * 8) ^ (dh & 56))];
                    o[tt] = __builtin_amdgcn_mfma_f32_16x16x32_bf16(va, pf, o[tt], 0, 0, 0);
                }
            }
        }
        __syncthreads();
    }
    // epilogue: O^T / l -> out[q][h*64+dh], pack pairs to b32 stores
    float inv = 1.0f / lrun;
    ushort_t* op = out + (size_t)qg * D + h * DH;
#pragma unroll
    for (int tt = 0; tt < 4; ++tt) {
#pragma unroll
        for (int rp = 0; rp < 2; ++rp) {
            int dd;
            float va = o[tt][2 * rp] * inv, vb = o[tt][2 * rp + 1] * inv;
            asm("v_cvt_pk_bf16_f32 %0, %1, %2" : "=v"(dd) : "v"(va), "v"(vb));
            *(int*)&op[tt * 16 + 4 * g + 2 * rp] = dd;
        }
    }
}

extern "C" void kernel_launch(void* const* d_in, const int* in_sizes, int n_in,
                              void* d_out, int out_size, void* d_ws, size_t ws_size,
                              hipStream_t stream) {
    const float* x    = (const float*)d_in[0];
    const float* Wqkv = (const float*)d_in[1];
    const float* bqkv = (const float*)d_in[2];
    const float* Wout = (const float*)d_in[3];
    const float* bout = (const float*)d_in[4];
    float* out = (float*)d_out;

    char* ws = (char*)d_ws;
    ushort_t* xb    = (ushort_t*)(ws);                       //  8 MB  x bf16
    ushort_t* wqkvT = (ushort_t*)(ws + (8u  << 20));         // 12 MB  Wqkv^T bf16 [3072][2048]
    ushort_t* woutT = (ushort_t*)(ws + (20u << 20));         //  8 MB  Wout^T bf16 [2048][2048]
    ushort_t* qkvb  = (ushort_t*)(ws + (28u << 20));         // 12 MB  qkv bf16 [2048][3072]
    ushort_t* ao    = (ushort_t*)(ws + (40u << 20));         //  8 MB  attn out bf16 [2048][2048]

    k_cvt<<<(S * D / 4 + 255) / 256, 256, 0, stream>>>(x, xb, S * D / 4);
    k_transpose_cvt<<<dim3(NQKV / 32, D / 32), dim3(32, 8), 0, stream>>>(Wqkv, wqkvT, D, NQKV);
    k_transpose_cvt<<<dim3(D / 32, D / 32), dim3(32, 8), 0, stream>>>(Wout, woutT, D, D);
    k_gemm<false><<<dim3(NQKV / 128, S / 128), 256, 0, stream>>>(xb, wqkvT, bqkv, qkvb, S, NQKV, D);
    k_rope<<<(S * 40 * 16) / 256, 256, 0, stream>>>(qkvb);
    k_attn<<<dim3(NH, 16), 512, 0, stream>>>(qkvb, ao);
    k_gemm<true><<<dim3(D / 128, S / 128), 256, 0, stream>>>(ao, woutT, bout, out, S, D, D);
}

// Round 6
// 282.998 us; speedup vs baseline: 1.2657x; 1.0269x over previous
//
#include <hip/hip_runtime.h>

typedef unsigned short ushort_t;
typedef __attribute__((ext_vector_type(8))) __bf16 bf16x8;
typedef __attribute__((ext_vector_type(4))) float f32x4;
typedef __attribute__((ext_vector_type(8))) unsigned short ushort8;
typedef __attribute__((ext_vector_type(4))) int int4v;

constexpr int S = 2048;
constexpr int D = 2048;
constexpr int NQKV = 3072;       // (32 + 2*8) * 64
constexpr int NH = 32, DH = 64;

static __device__ __forceinline__ float bf2f(ushort_t u) {
    return __uint_as_float(((unsigned int)u) << 16);
}
static __device__ __forceinline__ ushort_t f2bf(float f) {
    unsigned int u = __float_as_uint(f);
    u = (u + 0x7fffu + ((u >> 16) & 1u)) >> 16;   // round-to-nearest-even
    return (ushort_t)u;
}

#define GLD16(gp, sp)                                                          \
    __builtin_amdgcn_global_load_lds(                                          \
        (const __attribute__((address_space(1))) void*)(gp),                   \
        (__attribute__((address_space(3))) void*)(sp), 16, 0, 0)

// ---------- fp32 -> bf16 straight copy ----------
__global__ void k_cvt(const float* __restrict__ src, ushort_t* __restrict__ dst, int n4) {
    int i = blockIdx.x * blockDim.x + threadIdx.x;
    if (i < n4) {
        float4 v = ((const float4*)src)[i];
        ushort4 o;
        o.x = f2bf(v.x); o.y = f2bf(v.y); o.z = f2bf(v.z); o.w = f2bf(v.w);
        ((ushort4*)dst)[i] = o;
    }
}

// ---------- fp32 [R][C] -> bf16 [C][R] (transpose + convert) ----------
__global__ void k_transpose_cvt(const float* __restrict__ src, ushort_t* __restrict__ dst,
                                int R, int C) {
    __shared__ float tile[32][33];
    int c0 = blockIdx.x * 32, r0 = blockIdx.y * 32;
    int tx = threadIdx.x, ty = threadIdx.y;   // 32 x 8
#pragma unroll
    for (int j = 0; j < 32; j += 8)
        tile[ty + j][tx] = src[(size_t)(r0 + ty + j) * C + c0 + tx];
    __syncthreads();
#pragma unroll
    for (int j = 0; j < 32; j += 8)
        dst[(size_t)(c0 + ty + j) * R + r0 + tx] = f2bf(tile[tx][ty + j]);
}

// ---------- bf16 GEMM (m97 structure, GLD16 staging): C = A @ BT^T + bias ----------
// SINGLE-VARIABLE EXPERIMENT: this staging path is the only untested subsystem.
template <bool OUT_F32>
__global__ __launch_bounds__(256) void k_gemm(
    const ushort_t* __restrict__ A,   // [M][K] bf16
    const ushort_t* __restrict__ BT,  // [N][K] bf16
    const float* __restrict__ bias,   // [N]
    void* __restrict__ Cout,          // [M][N] f32 or bf16
    int M, int N, int K)
{
    constexpr int BK = 32;
    __shared__ ushort_t As[128 * BK];   // linear row*32+k (global_load_lds needs linear dest)
    __shared__ ushort_t Bs[128 * BK];
    const int m0 = blockIdx.y * 128;
    const int n0 = blockIdx.x * 128;
    const int t = threadIdx.x;
    const int lane = t & 63, wid = t >> 6;
    const int wm = (wid >> 1) * 64, wn = (wid & 1) * 64;
    const int lr = lane & 15, kg = (lane >> 4) * 8;

    // staging: wave wid covers rows [wid*32, wid*32+32) in two 16-row chunks.
    // global_load_lds lane l writes lds_base + l*16B -> row = base + (l>>2), colhw = (l&3)*8
    const int srow = lane >> 2;
    const int scol = (lane & 3) * 8;
    const ushort_t* gA = A + (size_t)(m0 + wid * 32 + srow) * K + scol;
    const ushort_t* gB = BT + (size_t)(n0 + wid * 32 + srow) * K + scol;
    ushort_t* lA = &As[(wid * 32) * BK];
    ushort_t* lB = &Bs[(wid * 32) * BK];

    f32x4 acc[4][4] = {};

    for (int k0 = 0; k0 < K; k0 += BK) {
        GLD16(gA + k0, lA);
        GLD16(gA + (size_t)16 * K + k0, lA + 16 * BK);
        GLD16(gB + k0, lB);
        GLD16(gB + (size_t)16 * K + k0, lB + 16 * BK);
        __syncthreads();
        bf16x8 af[4], bfr[4];
#pragma unroll
        for (int i = 0; i < 4; ++i) {
            af[i]  = *(const bf16x8*)&As[(wm + i * 16 + lr) * BK + kg];
            bfr[i] = *(const bf16x8*)&Bs[(wn + i * 16 + lr) * BK + kg];
        }
#pragma unroll
        for (int i = 0; i < 4; ++i)
#pragma unroll
            for (int j = 0; j < 4; ++j)
                acc[i][j] = __builtin_amdgcn_mfma_f32_16x16x32_bf16(af[i], bfr[j], acc[i][j], 0, 0, 0);
        __syncthreads();
    }

    const int lg = (lane >> 4) * 4;
#pragma unroll
    for (int j = 0; j < 4; ++j) {
        int n = n0 + wn + j * 16 + lr;
        float bv = bias[n];
#pragma unroll
        for (int i = 0; i < 4; ++i) {
#pragma unroll
            for (int r = 0; r < 4; ++r) {
                int m = m0 + wm + i * 16 + lg + r;
                float v = acc[i][j][r] + bv;
                if constexpr (OUT_F32) ((float*)Cout)[(size_t)m * N + n] = v;
                else ((ushort_t*)Cout)[(size_t)m * N + n] = f2bf(v);
            }
        }
    }
}

// ---------- RoPE in-place on bf16 qkv (q heads 0..31, k heads 32..39) ----------
__global__ void k_rope(ushort_t* qkv) {
    int idx = blockIdx.x * blockDim.x + threadIdx.x;   // S*40*16 threads
    int i = idx & 15;
    int sh = idx >> 4;
    int h = sh % 40;
    int s = sh / 40;
    if (s >= S) return;
    int col = (h < 32) ? h * 64 : 2048 + (h - 32) * 64;
    ushort_t* p = qkv + (size_t)s * NQKV + col;
    float x1 = bf2f(p[i]), x2 = bf2f(p[i + 16]);
    float inv = exp2f(-(float)i * 0.83048202372f);   // 10000^(-i/16)
    float f = (float)s * inv;
    float c, sn;
    sincosf(f, &sn, &c);
    p[i]      = f2bf(x1 * c - x2 * sn);
    p[i + 16] = f2bf(x1 * sn + x2 * c);
}

// ---------- flash-style causal GQA attention, swapped-operand S^T form ----------
// VERIFIED round 5 (passed, absmax 0.0156). Only change this round: qb remap so
// co-resident block pairs (by, by+8) have complementary tile counts (sum = 34).
__global__ __launch_bounds__(512) void k_attn(const ushort_t* __restrict__ qkv,
                                              ushort_t* __restrict__ out) {
    __shared__ ushort_t Ks[64 * 72];   // [kv][dh], stride 72 halfwords
    __shared__ ushort_t Vs[64 * 64];   // V^T swizzled: (dh,kv) at dh*64 + (kv ^ (dh&56))

    const int h = blockIdx.x;
    const int by = blockIdx.y;
    const int qb = (by < 8) ? by : 23 - by;   // pairs (by,by+8): qb sums = 15 -> balanced
    const int q0 = qb * 128;
    const int kvh = h >> 2;           // GQA group of 4
    const int t = threadIdx.x, lane = t & 63, w = t >> 6;
    const int lr = lane & 15, g = lane >> 4;
    const int qw = q0 + w * 16;
    const int qg = qw + lr;           // this lane's q row

    // Q as B-frag: lane holds Q[q=lr][d = g*8 + 32s + j]
    bf16x8 qf0, qf1;
    {
        const ushort_t* qp = qkv + (size_t)qg * NQKV + h * DH + g * 8;
        qf0 = *(const bf16x8*)&qp[0];
        qf1 = *(const bf16x8*)&qp[32];
    }
    // bpermute source-lane byte indices: source lane = 16*g_src + lr,
    // g_src0 = 2*(g&1) (serves j=0..3), g_src1 = 2*(g&1)+1 (serves j=4..7)
    const int idx0 = (lr + 16 * (2 * (g & 1))) << 2;
    const int idx1 = (lr + 16 * (2 * (g & 1) + 1)) << 2;
    const bool hi = (g >> 1) != 0;

    float mrun = -1e30f, lrun = 0.f;
    f32x4 o[4] = {};                  // O^T: dh = 16tt + 4g + reg, q = lr

    const int sr = t >> 3, sc = (t & 7) * 8;  // staging: row 0..63, col 0..56
    const ushort_t* gK = qkv + (size_t)sr * NQKV + 2048 + kvh * DH + sc;
    const ushort_t* gV = qkv + (size_t)sr * NQKV + 2560 + kvh * DH + sc;

    const int ntile = (q0 + 128) / 64;
    for (int kt = 0; kt < ntile; ++kt) {
        const int kv0 = kt * 64;
        {
            ushort8 kk = *(const ushort8*)&gK[(size_t)kv0 * NQKV];
            *(ushort8*)&Ks[sr * 72 + sc] = kk;
            ushort8 vv = *(const ushort8*)&gV[(size_t)kv0 * NQKV];
#pragma unroll
            for (int e = 0; e < 8; ++e) Vs[(sc + e) * 64 + (sr ^ sc)] = vv[e];
        }
        __syncthreads();
        if (kv0 <= qw) {              // wave has visible kv in this tile
            // S^T tile: A = K rows (contig), B = Q^T (from regs)
            f32x4 s[4];
#pragma unroll
            for (int nt = 0; nt < 4; ++nt) {
                bf16x8 a0 = *(const bf16x8*)&Ks[(nt * 16 + lr) * 72 + g * 8];
                bf16x8 a1 = *(const bf16x8*)&Ks[(nt * 16 + lr) * 72 + 32 + g * 8];
                f32x4 a = {};
                a = __builtin_amdgcn_mfma_f32_16x16x32_bf16(a0, qf0, a, 0, 0, 0);
                a = __builtin_amdgcn_mfma_f32_16x16x32_bf16(a1, qf1, a, 0, 0, 0);
                s[nt] = a;
            }
            // scale + causal mask + online softmax (lane holds S^T[16nt+4g+r][lr])
            float tmax = -3e38f;
#pragma unroll
            for (int nt = 0; nt < 4; ++nt)
#pragma unroll
                for (int r = 0; r < 4; ++r) {
                    float v = s[nt][r] * 0.125f;
                    int kvg = kv0 + nt * 16 + 4 * g + r;
                    v = (kvg > qg) ? -1e30f : v;
                    s[nt][r] = v;
                    tmax = fmaxf(tmax, v);
                }
            tmax = fmaxf(tmax, __shfl_xor(tmax, 16));
            tmax = fmaxf(tmax, __shfl_xor(tmax, 32));
            float mn = fmaxf(mrun, tmax);
            float alpha = __expf(mrun - mn);
            float sum = 0.f;
#pragma unroll
            for (int nt = 0; nt < 4; ++nt)
#pragma unroll
                for (int r = 0; r < 4; ++r) {
                    float p = __expf(s[nt][r] - mn);
                    s[nt][r] = p;
                    sum += p;
                }
            sum += __shfl_xor(sum, 16);
            sum += __shfl_xor(sum, 32);
            lrun = lrun * alpha + sum;
            mrun = mn;
#pragma unroll
            for (int tt = 0; tt < 4; ++tt) o[tt] *= alpha;

            // pack P^T to bf16 pairs: pk[nt*2+rp] = (r=2rp, r=2rp+1) of tile nt
            int pk[8];
#pragma unroll
            for (int nt = 0; nt < 4; ++nt)
#pragma unroll
                for (int rp = 0; rp < 2; ++rp) {
                    int dd;
                    asm("v_cvt_pk_bf16_f32 %0, %1, %2"
                        : "=v"(dd) : "v"(s[nt][2 * rp]), "v"(s[nt][2 * rp + 1]));
                    pk[nt * 2 + rp] = dd;
                }
            // redistribute to B-frag (kv = 32ks + 8g + j, q = lr) and PV.
            // dest needs nt = 2ks + (g>>1); register index must be lane-invariant,
            // so bpermute both candidates and cndmask-select.
#pragma unroll
            for (int ks = 0; ks < 2; ++ks) {
                int a0 = __builtin_amdgcn_ds_bpermute(idx0, pk[(2 * ks) * 2 + 0]);
                int b0 = __builtin_amdgcn_ds_bpermute(idx0, pk[(2 * ks + 1) * 2 + 0]);
                int a1 = __builtin_amdgcn_ds_bpermute(idx0, pk[(2 * ks) * 2 + 1]);
                int b1 = __builtin_amdgcn_ds_bpermute(idx0, pk[(2 * ks + 1) * 2 + 1]);
                int a2 = __builtin_amdgcn_ds_bpermute(idx1, pk[(2 * ks) * 2 + 0]);
                int b2 = __builtin_amdgcn_ds_bpermute(idx1, pk[(2 * ks + 1) * 2 + 0]);
                int a3 = __builtin_amdgcn_ds_bpermute(idx1, pk[(2 * ks) * 2 + 1]);
                int b3 = __builtin_amdgcn_ds_bpermute(idx1, pk[(2 * ks + 1) * 2 + 1]);
                int4v pb;
                pb.x = hi ? b0 : a0;   // j=0,1
                pb.y = hi ? b1 : a1;   // j=2,3
                pb.z = hi ? b2 : a2;   // j=4,5
                pb.w = hi ? b3 : a3;   // j=6,7
                bf16x8 pf = __builtin_bit_cast(bf16x8, pb);
#pragma unroll
                for (int tt = 0; tt < 4; ++tt) {
                    const int dh = tt * 16 + lr;
                    bf16x8 va = *(const bf16x8*)&Vs[dh * 64 + ((32 * ks + g * 8) ^ (dh & 56))];
                    o[tt] = __builtin_amdgcn_mfma_f32_16x16x32_bf16(va, pf, o[tt], 0, 0, 0);
                }
            }
        }
        __syncthreads();
    }
    // epilogue: O^T / l -> out[q][h*64+dh], pack pairs to b32 stores
    float inv = 1.0f / lrun;
    ushort_t* op = out + (size_t)qg * D + h * DH;
#pragma unroll
    for (int tt = 0; tt < 4; ++tt) {
#pragma unroll
        for (int rp = 0; rp < 2; ++rp) {
            int dd;
            float va = o[tt][2 * rp] * inv, vb = o[tt][2 * rp + 1] * inv;
            asm("v_cvt_pk_bf16_f32 %0, %1, %2" : "=v"(dd) : "v"(va), "v"(vb));
            *(int*)&op[tt * 16 + 4 * g + 2 * rp] = dd;
        }
    }
}

extern "C" void kernel_launch(void* const* d_in, const int* in_sizes, int n_in,
                              void* d_out, int out_size, void* d_ws, size_t ws_size,
                              hipStream_t stream) {
    const float* x    = (const float*)d_in[0];
    const float* Wqkv = (const float*)d_in[1];
    const float* bqkv = (const float*)d_in[2];
    const float* Wout = (const float*)d_in[3];
    const float* bout = (const float*)d_in[4];
    float* out = (float*)d_out;

    char* ws = (char*)d_ws;
    ushort_t* xb    = (ushort_t*)(ws);                       //  8 MB  x bf16
    ushort_t* wqkvT = (ushort_t*)(ws + (8u  << 20));         // 12 MB  Wqkv^T bf16 [3072][2048]
    ushort_t* woutT = (ushort_t*)(ws + (20u << 20));         //  8 MB  Wout^T bf16 [2048][2048]
    ushort_t* qkvb  = (ushort_t*)(ws + (28u << 20));         // 12 MB  qkv bf16 [2048][3072]
    ushort_t* ao    = (ushort_t*)(ws + (40u << 20));         //  8 MB  attn out bf16 [2048][2048]

    k_cvt<<<(S * D / 4 + 255) / 256, 256, 0, stream>>>(x, xb, S * D / 4);
    k_transpose_cvt<<<dim3(NQKV / 32, D / 32), dim3(32, 8), 0, stream>>>(Wqkv, wqkvT, D, NQKV);
    k_transpose_cvt<<<dim3(D / 32, D / 32), dim3(32, 8), 0, stream>>>(Wout, woutT, D, D);
    k_gemm<false><<<dim3(NQKV / 128, S / 128), 256, 0, stream>>>(xb, wqkvT, bqkv, qkvb, S, NQKV, D);
    k_rope<<<(S * 40 * 16) / 256, 256, 0, stream>>>(qkvb);
    k_attn<<<dim3(NH, 16), 512, 0, stream>>>(qkvb, ao);
    k_gemm<true><<<dim3(D / 128, S / 128), 256, 0, stream>>>(ao, woutT, bout, out, S, D, D);
}

// Round 8
// 272.158 us; speedup vs baseline: 1.3162x; 1.0398x over previous
//
#include <hip/hip_runtime.h>

typedef unsigned short ushort_t;
typedef __attribute__((ext_vector_type(8))) __bf16 bf16x8;
typedef __attribute__((ext_vector_type(4))) float f32x4;
typedef __attribute__((ext_vector_type(8))) unsigned short ushort8;
typedef __attribute__((ext_vector_type(4))) int int4v;

constexpr int S = 2048;
constexpr int D = 2048;
constexpr int NQKV = 3072;       // (32 + 2*8) * 64
constexpr int NH = 32, DH = 64;

static __device__ __forceinline__ float bf2f(ushort_t u) {
    return __uint_as_float(((unsigned int)u) << 16);
}
static __device__ __forceinline__ ushort_t f2bf(float f) {
    unsigned int u = __float_as_uint(f);
    u = (u + 0x7fffu + ((u >> 16) & 1u)) >> 16;   // round-to-nearest-even
    return (ushort_t)u;
}

#define GLD16(gp, sp)                                                          \
    __builtin_amdgcn_global_load_lds(                                          \
        (const __attribute__((address_space(1))) void*)(gp),                   \
        (__attribute__((address_space(3))) void*)(sp), 16, 0, 0)

// ---------- fp32 -> bf16 straight copy ----------
__global__ void k_cvt(const float* __restrict__ src, ushort_t* __restrict__ dst, int n4) {
    int i = blockIdx.x * blockDim.x + threadIdx.x;
    if (i < n4) {
        float4 v = ((const float4*)src)[i];
        ushort4 o;
        o.x = f2bf(v.x); o.y = f2bf(v.y); o.z = f2bf(v.z); o.w = f2bf(v.w);
        ((ushort4*)dst)[i] = o;
    }
}

// ---------- fp32 [R][C] -> bf16 [C][R] (transpose + convert) ----------
__global__ void k_transpose_cvt(const float* __restrict__ src, ushort_t* __restrict__ dst,
                                int R, int C) {
    __shared__ float tile[32][33];
    int c0 = blockIdx.x * 32, r0 = blockIdx.y * 32;
    int tx = threadIdx.x, ty = threadIdx.y;   // 32 x 8
#pragma unroll
    for (int j = 0; j < 32; j += 8)
        tile[ty + j][tx] = src[(size_t)(r0 + ty + j) * C + c0 + tx];
    __syncthreads();
#pragma unroll
    for (int j = 0; j < 32; j += 8)
        dst[(size_t)(c0 + ty + j) * R + r0 + tx] = f2bf(tile[tx][ty + j]);
}

// ---------- bf16 GEMM: GLD16 + 2-phase double-buffer (T3 minimum) ----------
// At these shapes grid is 1-1.5 blocks/CU (no TLP); the dbuf overlaps the
// next tile's global->LDS DMA with the current tile's ds_read+MFMA (ILP).
// Correctness note: __syncthreads() emits a full vmcnt/lgkmcnt drain before
// s_barrier, so the DMA is published even if the explicit asm wait moves.
template <bool OUT_F32>
__global__ __launch_bounds__(256) void k_gemm(
    const ushort_t* __restrict__ A,   // [M][K] bf16
    const ushort_t* __restrict__ BT,  // [N][K] bf16
    const float* __restrict__ bias,   // [N]
    void* __restrict__ Cout,          // [M][N] f32 or bf16
    int M, int N, int K)
{
    constexpr int BK = 32;
    __shared__ ushort_t As[2][128 * BK];   // linear row*32+k per buffer
    __shared__ ushort_t Bs[2][128 * BK];
    const int m0 = blockIdx.y * 128;
    const int n0 = blockIdx.x * 128;
    const int t = threadIdx.x;
    const int lane = t & 63, wid = t >> 6;
    const int wm = (wid >> 1) * 64, wn = (wid & 1) * 64;
    const int lr = lane & 15, kg = (lane >> 4) * 8;

    // staging: wave wid covers rows [wid*32, wid*32+32) in two 16-row chunks.
    // global_load_lds lane l writes lds_base + l*16B -> row = l>>2, colhw = (l&3)*8
    const int srow = lane >> 2;
    const int scol = (lane & 3) * 8;
    const ushort_t* gA = A + (size_t)(m0 + wid * 32 + srow) * K + scol;
    const ushort_t* gB = BT + (size_t)(n0 + wid * 32 + srow) * K + scol;
    const int lofs = (wid * 32) * BK;

#define STAGE(buf, kk)                                                         \
    do {                                                                       \
        GLD16(gA + (kk), &As[buf][lofs]);                                      \
        GLD16(gA + (size_t)16 * K + (kk), &As[buf][lofs + 16 * BK]);           \
        GLD16(gB + (kk), &Bs[buf][lofs]);                                      \
        GLD16(gB + (size_t)16 * K + (kk), &Bs[buf][lofs + 16 * BK]);           \
    } while (0)

    f32x4 acc[4][4] = {};

    STAGE(0, 0);
    asm volatile("s_waitcnt vmcnt(0)");
    __syncthreads();

    int cur = 0;
    for (int k0 = 0; k0 < K; k0 += BK) {
        if (k0 + BK < K) STAGE(cur ^ 1, k0 + BK);   // overlap next DMA with compute
        bf16x8 af[4], bfr[4];
#pragma unroll
        for (int i = 0; i < 4; ++i) {
            af[i]  = *(const bf16x8*)&As[cur][(wm + i * 16 + lr) * BK + kg];
            bfr[i] = *(const bf16x8*)&Bs[cur][(wn + i * 16 + lr) * BK + kg];
        }
#pragma unroll
        for (int i = 0; i < 4; ++i)
#pragma unroll
            for (int j = 0; j < 4; ++j)
                acc[i][j] = __builtin_amdgcn_mfma_f32_16x16x32_bf16(af[i], bfr[j], acc[i][j], 0, 0, 0);
        asm volatile("s_waitcnt vmcnt(0)");   // this wave's next-buf DMA done
        __syncthreads();                      // all waves done reading cur + writing cur^1
        cur ^= 1;
    }
#undef STAGE

    const int lg = (lane >> 4) * 4;
#pragma unroll
    for (int j = 0; j < 4; ++j) {
        int n = n0 + wn + j * 16 + lr;
        float bv = bias[n];
#pragma unroll
        for (int i = 0; i < 4; ++i) {
#pragma unroll
            for (int r = 0; r < 4; ++r) {
                int m = m0 + wm + i * 16 + lg + r;
                float v = acc[i][j][r] + bv;
                if constexpr (OUT_F32) ((float*)Cout)[(size_t)m * N + n] = v;
                else ((ushort_t*)Cout)[(size_t)m * N + n] = f2bf(v);
            }
        }
    }
}

// ---------- RoPE in-place on bf16 qkv (q heads 0..31, k heads 32..39) ----------
__global__ void k_rope(ushort_t* qkv) {
    int idx = blockIdx.x * blockDim.x + threadIdx.x;   // S*40*16 threads
    int i = idx & 15;
    int sh = idx >> 4;
    int h = sh % 40;
    int s = sh / 40;
    if (s >= S) return;
    int col = (h < 32) ? h * 64 : 2048 + (h - 32) * 64;
    ushort_t* p = qkv + (size_t)s * NQKV + col;
    float x1 = bf2f(p[i]), x2 = bf2f(p[i + 16]);
    float inv = exp2f(-(float)i * 0.83048202372f);   // 10000^(-i/16)
    float f = (float)s * inv;
    float c, sn;
    sincosf(f, &sn, &c);
    p[i]      = f2bf(x1 * c - x2 * sn);
    p[i + 16] = f2bf(x1 * sn + x2 * c);
}

// ---------- flash-style causal GQA attention, swapped-operand S^T form ----------
// VERIFIED rounds 5-6 (absmax 0.0156, 79.2 us). Unchanged this round.
__global__ __launch_bounds__(512) void k_attn(const ushort_t* __restrict__ qkv,
                                              ushort_t* __restrict__ out) {
    __shared__ ushort_t Ks[64 * 72];   // [kv][dh], stride 72 halfwords
    __shared__ ushort_t Vs[64 * 64];   // V^T swizzled: (dh,kv) at dh*64 + (kv ^ (dh&56))

    const int h = blockIdx.x;
    const int by = blockIdx.y;
    const int qb = (by < 8) ? by : 23 - by;   // pairs (by,by+8): balanced critical path
    const int q0 = qb * 128;
    const int kvh = h >> 2;           // GQA group of 4
    const int t = threadIdx.x, lane = t & 63, w = t >> 6;
    const int lr = lane & 15, g = lane >> 4;
    const int qw = q0 + w * 16;
    const int qg = qw + lr;           // this lane's q row

    // Q as B-frag: lane holds Q[q=lr][d = g*8 + 32s + j]
    bf16x8 qf0, qf1;
    {
        const ushort_t* qp = qkv + (size_t)qg * NQKV + h * DH + g * 8;
        qf0 = *(const bf16x8*)&qp[0];
        qf1 = *(const bf16x8*)&qp[32];
    }
    // bpermute source-lane byte indices: source lane = 16*g_src + lr,
    // g_src0 = 2*(g&1) (serves j=0..3), g_src1 = 2*(g&1)+1 (serves j=4..7)
    const int idx0 = (lr + 16 * (2 * (g & 1))) << 2;
    const int idx1 = (lr + 16 * (2 * (g & 1) + 1)) << 2;
    const bool hi = (g >> 1) != 0;

    float mrun = -1e30f, lrun = 0.f;
    f32x4 o[4] = {};                  // O^T: dh = 16tt + 4g + reg, q = lr

    const int sr = t >> 3, sc = (t & 7) * 8;  // staging: row 0..63, col 0..56
    const ushort_t* gK = qkv + (size_t)sr * NQKV + 2048 + kvh * DH + sc;
    const ushort_t* gV = qkv + (size_t)sr * NQKV + 2560 + kvh * DH + sc;

    const int ntile = (q0 + 128) / 64;
    for (int kt = 0; kt < ntile; ++kt) {
        const int kv0 = kt * 64;
        {
            ushort8 kk = *(const ushort8*)&gK[(size_t)kv0 * NQKV];
            *(ushort8*)&Ks[sr * 72 + sc] = kk;
            ushort8 vv = *(const ushort8*)&gV[(size_t)kv0 * NQKV];
#pragma unroll
            for (int e = 0; e < 8; ++e) Vs[(sc + e) * 64 + (sr ^ sc)] = vv[e];
        }
        __syncthreads();
        if (kv0 <= qw) {              // wave has visible kv in this tile
            // S^T tile: A = K rows (contig), B = Q^T (from regs)
            f32x4 s[4];
#pragma unroll
            for (int nt = 0; nt < 4; ++nt) {
                bf16x8 a0 = *(const bf16x8*)&Ks[(nt * 16 + lr) * 72 + g * 8];
                bf16x8 a1 = *(const bf16x8*)&Ks[(nt * 16 + lr) * 72 + 32 + g * 8];
                f32x4 a = {};
                a = __builtin_amdgcn_mfma_f32_16x16x32_bf16(a0, qf0, a, 0, 0, 0);
                a = __builtin_amdgcn_mfma_f32_16x16x32_bf16(a1, qf1, a, 0, 0, 0);
                s[nt] = a;
            }
            // scale + causal mask + online softmax (lane holds S^T[16nt+4g+r][lr])
            float tmax = -3e38f;
#pragma unroll
            for (int nt = 0; nt < 4; ++nt)
#pragma unroll
                for (int r = 0; r < 4; ++r) {
                    float v = s[nt][r] * 0.125f;
                    int kvg = kv0 + nt * 16 + 4 * g + r;
                    v = (kvg > qg) ? -1e30f : v;
                    s[nt][r] = v;
                    tmax = fmaxf(tmax, v);
                }
            tmax = fmaxf(tmax, __shfl_xor(tmax, 16));
            tmax = fmaxf(tmax, __shfl_xor(tmax, 32));
            float mn = fmaxf(mrun, tmax);
            float alpha = __expf(mrun - mn);
            float sum = 0.f;
#pragma unroll
            for (int nt = 0; nt < 4; ++nt)
#pragma unroll
                for (int r = 0; r < 4; ++r) {
                    float p = __expf(s[nt][r] - mn);
                    s[nt][r] = p;
                    sum += p;
                }
            sum += __shfl_xor(sum, 16);
            sum += __shfl_xor(sum, 32);
            lrun = lrun * alpha + sum;
            mrun = mn;
#pragma unroll
            for (int tt = 0; tt < 4; ++tt) o[tt] *= alpha;

            // pack P^T to bf16 pairs: pk[nt*2+rp] = (r=2rp, r=2rp+1) of tile nt
            int pk[8];
#pragma unroll
            for (int nt = 0; nt < 4; ++nt)
#pragma unroll
                for (int rp = 0; rp < 2; ++rp) {
                    int dd;
                    asm("v_cvt_pk_bf16_f32 %0, %1, %2"
                        : "=v"(dd) : "v"(s[nt][2 * rp]), "v"(s[nt][2 * rp + 1]));
                    pk[nt * 2 + rp] = dd;
                }
            // redistribute to B-frag (kv = 32ks + 8g + j, q = lr) and PV.
            // bpermute register operands are compile-time pk[] indices;
            // dest-side cndmask-select by hi = g>>1 (lane-invariant rule).
#pragma unroll
            for (int ks = 0; ks < 2; ++ks) {
                int a0 = __builtin_amdgcn_ds_bpermute(idx0, pk[(2 * ks) * 2 + 0]);
                int b0 = __builtin_amdgcn_ds_bpermute(idx0, pk[(2 * ks + 1) * 2 + 0]);
                int a1 = __builtin_amdgcn_ds_bpermute(idx0, pk[(2 * ks) * 2 + 1]);
                int b1 = __builtin_amdgcn_ds_bpermute(idx0, pk[(2 * ks + 1) * 2 + 1]);
                int a2 = __builtin_amdgcn_ds_bpermute(idx1, pk[(2 * ks) * 2 + 0]);
                int b2 = __builtin_amdgcn_ds_bpermute(idx1, pk[(2 * ks + 1) * 2 + 0]);
                int a3 = __builtin_amdgcn_ds_bpermute(idx1, pk[(2 * ks) * 2 + 1]);
                int b3 = __builtin_amdgcn_ds_bpermute(idx1, pk[(2 * ks + 1) * 2 + 1]);
                int4v pb;
                pb.x = hi ? b0 : a0;   // j=0,1
                pb.y = hi ? b1 : a1;   // j=2,3
                pb.z = hi ? b2 : a2;   // j=4,5
                pb.w = hi ? b3 : a3;   // j=6,7
                bf16x8 pf = __builtin_bit_cast(bf16x8, pb);
#pragma unroll
                for (int tt = 0; tt < 4; ++tt) {
                    const int dh = tt * 16 + lr;
                    bf16x8 va = *(const bf16x8*)&Vs[dh * 64 + ((32 * ks + g * 8) ^ (dh & 56))];
                    o[tt] = __builtin_amdgcn_mfma_f32_16x16x32_bf16(va, pf, o[tt], 0, 0, 0);
                }
            }
        }
        __syncthreads();
    }
    // epilogue: O^T / l -> out[q][h*64+dh], pack pairs to b32 stores
    float inv = 1.0f / lrun;
    ushort_t* op = out + (size_t)qg * D + h * DH;
#pragma unroll
    for (int tt = 0; tt < 4; ++tt) {
#pragma unroll
        for (int rp = 0; rp < 2; ++rp) {
            int dd;
            float va = o[tt][2 * rp] * inv, vb = o[tt][2 * rp + 1] * inv;
            asm("v_cvt_pk_bf16_f32 %0, %1, %2" : "=v"(dd) : "v"(va), "v"(vb));
            *(int*)&op[tt * 16 + 4 * g + 2 * rp] = dd;
        }
    }
}

extern "C" void kernel_launch(void* const* d_in, const int* in_sizes, int n_in,
                              void* d_out, int out_size, void* d_ws, size_t ws_size,
                              hipStream_t stream) {
    const float* x    = (const float*)d_in[0];
    const float* Wqkv = (const float*)d_in[1];
    const float* bqkv = (const float*)d_in[2];
    const float* Wout = (const float*)d_in[3];
    const float* bout = (const float*)d_in[4];
    float* out = (float*)d_out;

    char* ws = (char*)d_ws;
    ushort_t* xb    = (ushort_t*)(ws);                       //  8 MB  x bf16
    ushort_t* wqkvT = (ushort_t*)(ws + (8u  << 20));         // 12 MB  Wqkv^T bf16 [3072][2048]
    ushort_t* woutT = (ushort_t*)(ws + (20u << 20));         //  8 MB  Wout^T bf16 [2048][2048]
    ushort_t* qkvb  = (ushort_t*)(ws + (28u << 20));         // 12 MB  qkv bf16 [2048][3072]
    ushort_t* ao    = (ushort_t*)(ws + (40u << 20));         //  8 MB  attn out bf16 [2048][2048]

    k_cvt<<<(S * D / 4 + 255) / 256, 256, 0, stream>>>(x, xb, S * D / 4);
    k_transpose_cvt<<<dim3(NQKV / 32, D / 32), dim3(32, 8), 0, stream>>>(Wqkv, wqkvT, D, NQKV);
    k_transpose_cvt<<<dim3(D / 32, D / 32), dim3(32, 8), 0, stream>>>(Wout, woutT, D, D);
    k_gemm<false><<<dim3(NQKV / 128, S / 128), 256, 0, stream>>>(xb, wqkvT, bqkv, qkvb, S, NQKV, D);
    k_rope<<<(S * 40 * 16) / 256, 256, 0, stream>>>(qkvb);
    k_attn<<<dim3(NH, 16), 512, 0, stream>>>(qkvb, ao);
    k_gemm<true><<<dim3(D / 128, S / 128), 256, 0, stream>>>(ao, woutT, bout, out, S, D, D);
}

// Round 9
// 264.073 us; speedup vs baseline: 1.3564x; 1.0306x over previous
//
#include <hip/hip_runtime.h>

typedef unsigned short ushort_t;
typedef __attribute__((ext_vector_type(8))) __bf16 bf16x8;
typedef __attribute__((ext_vector_type(4))) float f32x4;
typedef __attribute__((ext_vector_type(8))) unsigned short ushort8;
typedef __attribute__((ext_vector_type(4))) int int4v;

constexpr int S = 2048;
constexpr int D = 2048;
constexpr int NQKV = 3072;       // (32 + 2*8) * 64
constexpr int NH = 32, DH = 64;

static __device__ __forceinline__ float bf2f(ushort_t u) {
    return __uint_as_float(((unsigned int)u) << 16);
}
static __device__ __forceinline__ ushort_t f2bf(float f) {
    unsigned int u = __float_as_uint(f);
    u = (u + 0x7fffu + ((u >> 16) & 1u)) >> 16;   // round-to-nearest-even
    return (ushort_t)u;
}

#define GLD16(gp, sp)                                                          \
    __builtin_amdgcn_global_load_lds(                                          \
        (const __attribute__((address_space(1))) void*)(gp),                   \
        (__attribute__((address_space(3))) void*)(sp), 16, 0, 0)

// ---------- fp32 -> bf16 straight copy ----------
__global__ void k_cvt(const float* __restrict__ src, ushort_t* __restrict__ dst, int n4) {
    int i = blockIdx.x * blockDim.x + threadIdx.x;
    if (i < n4) {
        float4 v = ((const float4*)src)[i];
        ushort4 o;
        o.x = f2bf(v.x); o.y = f2bf(v.y); o.z = f2bf(v.z); o.w = f2bf(v.w);
        ((ushort4*)dst)[i] = o;
    }
}

// ---------- fp32 [R][C] -> bf16 [C][R] (transpose + convert) ----------
__global__ void k_transpose_cvt(const float* __restrict__ src, ushort_t* __restrict__ dst,
                                int R, int C) {
    __shared__ float tile[32][33];
    int c0 = blockIdx.x * 32, r0 = blockIdx.y * 32;
    int tx = threadIdx.x, ty = threadIdx.y;   // 32 x 8
#pragma unroll
    for (int j = 0; j < 32; j += 8)
        tile[ty + j][tx] = src[(size_t)(r0 + ty + j) * C + c0 + tx];
    __syncthreads();
#pragma unroll
    for (int j = 0; j < 32; j += 8)
        dst[(size_t)(c0 + ty + j) * R + r0 + tx] = f2bf(tile[tx][ty + j]);
}

// ---------- bf16 GEMM: GLD16 + 3-stage pipeline, counted vmcnt (T3+T4) ----------
// __syncthreads() drains vmcnt(0) at every barrier (defeats prefetch), so this
// uses raw s_barrier + counted vmcnt: loads for step i+2 stay in flight across
// barriers; vmcnt(8) confirms step-i's batch (4 loads/wave/step) has landed
// in LDS for ALL waves before any wave reads it (confirm-then-barrier order).
template <bool OUT_F32>
__global__ __launch_bounds__(256) void k_gemm(
    const ushort_t* __restrict__ A,   // [M][K] bf16
    const ushort_t* __restrict__ BT,  // [N][K] bf16
    const float* __restrict__ bias,   // [N]
    void* __restrict__ Cout,          // [M][N] f32 or bf16
    int M, int N, int K)
{
    constexpr int BK = 32;
    __shared__ ushort_t As[3][128 * BK];   // 48 KB total (A+B)
    __shared__ ushort_t Bs[3][128 * BK];
    const int m0 = blockIdx.y * 128;
    const int n0 = blockIdx.x * 128;
    const int t = threadIdx.x;
    const int lane = t & 63, wid = t >> 6;
    const int wm = (wid >> 1) * 64, wn = (wid & 1) * 64;
    const int lr = lane & 15, kg = (lane >> 4) * 8;

    // staging: wave wid covers rows [wid*32, wid*32+32) in two 16-row chunks.
    // global_load_lds lane l writes lds_base + l*16B -> row = l>>2, colhw = (l&3)*8
    const int srow = lane >> 2;
    const int scol = (lane & 3) * 8;
    const ushort_t* gA = A + (size_t)(m0 + wid * 32 + srow) * K + scol;
    const ushort_t* gB = BT + (size_t)(n0 + wid * 32 + srow) * K + scol;
    const int lofs = (wid * 32) * BK;

#define STAGE(buf, kk)                                                         \
    do {                                                                       \
        GLD16(gA + (kk), &As[buf][lofs]);                                      \
        GLD16(gA + (size_t)16 * K + (kk), &As[buf][lofs + 16 * BK]);           \
        GLD16(gB + (kk), &Bs[buf][lofs]);                                      \
        GLD16(gB + (size_t)16 * K + (kk), &Bs[buf][lofs + 16 * BK]);           \
    } while (0)

#define COMPUTE(bufi)                                                          \
    do {                                                                       \
        bf16x8 af[4], bfr[4];                                                  \
        _Pragma("unroll")                                                      \
        for (int i = 0; i < 4; ++i) {                                          \
            af[i]  = *(const bf16x8*)&As[bufi][(wm + i * 16 + lr) * BK + kg];  \
            bfr[i] = *(const bf16x8*)&Bs[bufi][(wn + i * 16 + lr) * BK + kg];  \
        }                                                                      \
        _Pragma("unroll")                                                      \
        for (int i = 0; i < 4; ++i)                                            \
            _Pragma("unroll")                                                  \
            for (int j = 0; j < 4; ++j)                                        \
                acc[i][j] = __builtin_amdgcn_mfma_f32_16x16x32_bf16(           \
                    af[i], bfr[j], acc[i][j], 0, 0, 0);                        \
    } while (0)

    f32x4 acc[4][4] = {};
    const int NK = K / BK;   // >= 3 for all our shapes (64)

    STAGE(0, 0);
    STAGE(1, BK);
    int cur = 0;
    for (int i = 0; i < NK - 2; ++i) {
        int nbuf = cur + 2; if (nbuf >= 3) nbuf -= 3;
        STAGE(nbuf, (i + 2) * BK);                      // step i+2 in flight
        asm volatile("s_waitcnt vmcnt(8)" ::: "memory"); // step i's 4 landed
        __builtin_amdgcn_s_barrier();                    // ... for all waves
        COMPUTE(cur);
        asm volatile("" ::: "memory");                   // pin ds_reads above
        __builtin_amdgcn_s_barrier();                    // all done reading cur
        ++cur; if (cur == 3) cur = 0;
    }
    // tail step NK-2: nothing staged this iter -> only step NK-1's 4 may remain
    asm volatile("s_waitcnt vmcnt(4)" ::: "memory");
    __builtin_amdgcn_s_barrier();
    COMPUTE(cur);
    asm volatile("" ::: "memory");
    __builtin_amdgcn_s_barrier();
    ++cur; if (cur == 3) cur = 0;
    // tail step NK-1
    asm volatile("s_waitcnt vmcnt(0)" ::: "memory");
    __builtin_amdgcn_s_barrier();
    COMPUTE(cur);
#undef STAGE
#undef COMPUTE

    const int lg = (lane >> 4) * 4;
#pragma unroll
    for (int j = 0; j < 4; ++j) {
        int n = n0 + wn + j * 16 + lr;
        float bv = bias[n];
#pragma unroll
        for (int i = 0; i < 4; ++i) {
#pragma unroll
            for (int r = 0; r < 4; ++r) {
                int m = m0 + wm + i * 16 + lg + r;
                float v = acc[i][j][r] + bv;
                if constexpr (OUT_F32) ((float*)Cout)[(size_t)m * N + n] = v;
                else ((ushort_t*)Cout)[(size_t)m * N + n] = f2bf(v);
            }
        }
    }
}

// ---------- RoPE in-place on bf16 qkv (q heads 0..31, k heads 32..39) ----------
__global__ void k_rope(ushort_t* qkv) {
    int idx = blockIdx.x * blockDim.x + threadIdx.x;   // S*40*16 threads
    int i = idx & 15;
    int sh = idx >> 4;
    int h = sh % 40;
    int s = sh / 40;
    if (s >= S) return;
    int col = (h < 32) ? h * 64 : 2048 + (h - 32) * 64;
    ushort_t* p = qkv + (size_t)s * NQKV + col;
    float x1 = bf2f(p[i]), x2 = bf2f(p[i + 16]);
    float inv = exp2f(-(float)i * 0.83048202372f);   // 10000^(-i/16)
    float f = (float)s * inv;
    float c, sn;
    sincosf(f, &sn, &c);
    p[i]      = f2bf(x1 * c - x2 * sn);
    p[i + 16] = f2bf(x1 * sn + x2 * c);
}

// ---------- flash-style causal GQA attention, swapped-operand S^T form ----------
// VERIFIED rounds 5-8 (absmax 0.0156). This round: T14 async-STAGE split only —
// next tile's K/V global loads issue AFTER the publish barrier (latency hides
// under compute), LDS write moves to top of next iter. Indexing unchanged.
__global__ __launch_bounds__(512) void k_attn(const ushort_t* __restrict__ qkv,
                                              ushort_t* __restrict__ out) {
    __shared__ ushort_t Ks[64 * 72];   // [kv][dh], stride 72 halfwords
    __shared__ ushort_t Vs[64 * 64];   // V^T swizzled: (dh,kv) at dh*64 + (kv ^ (dh&56))

    const int h = blockIdx.x;
    const int by = blockIdx.y;
    const int qb = (by < 8) ? by : 23 - by;   // pairs (by,by+8): balanced critical path
    const int q0 = qb * 128;
    const int kvh = h >> 2;           // GQA group of 4
    const int t = threadIdx.x, lane = t & 63, w = t >> 6;
    const int lr = lane & 15, g = lane >> 4;
    const int qw = q0 + w * 16;
    const int qg = qw + lr;           // this lane's q row

    // Q as B-frag: lane holds Q[q=lr][d = g*8 + 32s + j]
    bf16x8 qf0, qf1;
    {
        const ushort_t* qp = qkv + (size_t)qg * NQKV + h * DH + g * 8;
        qf0 = *(const bf16x8*)&qp[0];
        qf1 = *(const bf16x8*)&qp[32];
    }
    // bpermute source-lane byte indices: source lane = 16*g_src + lr,
    // g_src0 = 2*(g&1) (serves j=0..3), g_src1 = 2*(g&1)+1 (serves j=4..7)
    const int idx0 = (lr + 16 * (2 * (g & 1))) << 2;
    const int idx1 = (lr + 16 * (2 * (g & 1) + 1)) << 2;
    const bool hi = (g >> 1) != 0;

    float mrun = -1e30f, lrun = 0.f;
    f32x4 o[4] = {};                  // O^T: dh = 16tt + 4g + reg, q = lr

    const int sr = t >> 3, sc = (t & 7) * 8;  // staging: row 0..63, col 0..56
    const ushort_t* gK = qkv + (size_t)sr * NQKV + 2048 + kvh * DH + sc;
    const ushort_t* gV = qkv + (size_t)sr * NQKV + 2560 + kvh * DH + sc;

    const int ntile = (q0 + 128) / 64;
    ushort8 kk = *(const ushort8*)&gK[0];       // tile 0 pre-load
    ushort8 vv = *(const ushort8*)&gV[0];
    for (int kt = 0; kt < ntile; ++kt) {
        const int kv0 = kt * 64;
        {   // write previously-loaded tile to LDS
            *(ushort8*)&Ks[sr * 72 + sc] = kk;
#pragma unroll
            for (int e = 0; e < 8; ++e) Vs[(sc + e) * 64 + (sr ^ sc)] = vv[e];
        }
        __syncthreads();
        if (kt + 1 < ntile) {   // T14: issue next tile's loads, hide under compute
            kk = *(const ushort8*)&gK[(size_t)(kv0 + 64) * NQKV];
            vv = *(const ushort8*)&gV[(size_t)(kv0 + 64) * NQKV];
        }
        if (kv0 <= qw) {              // wave has visible kv in this tile
            // S^T tile: A = K rows (contig), B = Q^T (from regs)
            f32x4 s[4];
#pragma unroll
            for (int nt = 0; nt < 4; ++nt) {
                bf16x8 a0 = *(const bf16x8*)&Ks[(nt * 16 + lr) * 72 + g * 8];
                bf16x8 a1 = *(const bf16x8*)&Ks[(nt * 16 + lr) * 72 + 32 + g * 8];
                f32x4 a = {};
                a = __builtin_amdgcn_mfma_f32_16x16x32_bf16(a0, qf0, a, 0, 0, 0);
                a = __builtin_amdgcn_mfma_f32_16x16x32_bf16(a1, qf1, a, 0, 0, 0);
                s[nt] = a;
            }
            // scale + causal mask + online softmax (lane holds S^T[16nt+4g+r][lr])
            float tmax = -3e38f;
#pragma unroll
            for (int nt = 0; nt < 4; ++nt)
#pragma unroll
                for (int r = 0; r < 4; ++r) {
                    float v = s[nt][r] * 0.125f;
                    int kvg = kv0 + nt * 16 + 4 * g + r;
                    v = (kvg > qg) ? -1e30f : v;
                    s[nt][r] = v;
                    tmax = fmaxf(tmax, v);
                }
            tmax = fmaxf(tmax, __shfl_xor(tmax, 16));
            tmax = fmaxf(tmax, __shfl_xor(tmax, 32));
            float mn = fmaxf(mrun, tmax);
            float alpha = __expf(mrun - mn);
            float sum = 0.f;
#pragma unroll
            for (int nt = 0; nt < 4; ++nt)
#pragma unroll
                for (int r = 0; r < 4; ++r) {
                    float p = __expf(s[nt][r] - mn);
                    s[nt][r] = p;
                    sum += p;
                }
            sum += __shfl_xor(sum, 16);
            sum += __shfl_xor(sum, 32);
            lrun = lrun * alpha + sum;
            mrun = mn;
#pragma unroll
            for (int tt = 0; tt < 4; ++tt) o[tt] *= alpha;

            // pack P^T to bf16 pairs: pk[nt*2+rp] = (r=2rp, r=2rp+1) of tile nt
            int pk[8];
#pragma unroll
            for (int nt = 0; nt < 4; ++nt)
#pragma unroll
                for (int rp = 0; rp < 2; ++rp) {
                    int dd;
                    asm("v_cvt_pk_bf16_f32 %0, %1, %2"
                        : "=v"(dd) : "v"(s[nt][2 * rp]), "v"(s[nt][2 * rp + 1]));
                    pk[nt * 2 + rp] = dd;
                }
            // redistribute to B-frag (kv = 32ks + 8g + j, q = lr) and PV.
            // bpermute register operands are compile-time pk[] indices;
            // dest-side cndmask-select by hi = g>>1 (lane-invariant rule).
#pragma unroll
            for (int ks = 0; ks < 2; ++ks) {
                int a0 = __builtin_amdgcn_ds_bpermute(idx0, pk[(2 * ks) * 2 + 0]);
                int b0 = __builtin_amdgcn_ds_bpermute(idx0, pk[(2 * ks + 1) * 2 + 0]);
                int a1 = __builtin_amdgcn_ds_bpermute(idx0, pk[(2 * ks) * 2 + 1]);
                int b1 = __builtin_amdgcn_ds_bpermute(idx0, pk[(2 * ks + 1) * 2 + 1]);
                int a2 = __builtin_amdgcn_ds_bpermute(idx1, pk[(2 * ks) * 2 + 0]);
                int b2 = __builtin_amdgcn_ds_bpermute(idx1, pk[(2 * ks + 1) * 2 + 0]);
                int a3 = __builtin_amdgcn_ds_bpermute(idx1, pk[(2 * ks) * 2 + 1]);
                int b3 = __builtin_amdgcn_ds_bpermute(idx1, pk[(2 * ks + 1) * 2 + 1]);
                int4v pb;
                pb.x = hi ? b0 : a0;   // j=0,1
                pb.y = hi ? b1 : a1;   // j=2,3
                pb.z = hi ? b2 : a2;   // j=4,5
                pb.w = hi ? b3 : a3;   // j=6,7
                bf16x8 pf = __builtin_bit_cast(bf16x8, pb);
#pragma unroll
                for (int tt = 0; tt < 4; ++tt) {
                    const int dh = tt * 16 + lr;
                    bf16x8 va = *(const bf16x8*)&Vs[dh * 64 + ((32 * ks + g * 8) ^ (dh & 56))];
                    o[tt] = __builtin_amdgcn_mfma_f32_16x16x32_bf16(va, pf, o[tt], 0, 0, 0);
                }
            }
        }
        __syncthreads();
    }
    // epilogue: O^T / l -> out[q][h*64+dh], pack pairs to b32 stores
    float inv = 1.0f / lrun;
    ushort_t* op = out + (size_t)qg * D + h * DH;
#pragma unroll
    for (int tt = 0; tt < 4; ++tt) {
#pragma unroll
        for (int rp = 0; rp < 2; ++rp) {
            int dd;
            float va = o[tt][2 * rp] * inv, vb = o[tt][2 * rp + 1] * inv;
            asm("v_cvt_pk_bf16_f32 %0, %1, %2" : "=v"(dd) : "v"(va), "v"(vb));
            *(int*)&op[tt * 16 + 4 * g + 2 * rp] = dd;
        }
    }
}

extern "C" void kernel_launch(void* const* d_in, const int* in_sizes, int n_in,
                              void* d_out, int out_size, void* d_ws, size_t ws_size,
                              hipStream_t stream) {
    const float* x    = (const float*)d_in[0];
    const float* Wqkv = (const float*)d_in[1];
    const float* bqkv = (const float*)d_in[2];
    const float* Wout = (const float*)d_in[3];
    const float* bout = (const float*)d_in[4];
    float* out = (float*)d_out;

    char* ws = (char*)d_ws;
    ushort_t* xb    = (ushort_t*)(ws);                       //  8 MB  x bf16
    ushort_t* wqkvT = (ushort_t*)(ws + (8u  << 20));         // 12 MB  Wqkv^T bf16 [3072][2048]
    ushort_t* woutT = (ushort_t*)(ws + (20u << 20));         //  8 MB  Wout^T bf16 [2048][2048]
    ushort_t* qkvb  = (ushort_t*)(ws + (28u << 20));         // 12 MB  qkv bf16 [2048][3072]
    ushort_t* ao    = (ushort_t*)(ws + (40u << 20));         //  8 MB  attn out bf16 [2048][2048]

    k_cvt<<<(S * D / 4 + 255) / 256, 256, 0, stream>>>(x, xb, S * D / 4);
    k_transpose_cvt<<<dim3(NQKV / 32, D / 32), dim3(32, 8), 0, stream>>>(Wqkv, wqkvT, D, NQKV);
    k_transpose_cvt<<<dim3(D / 32, D / 32), dim3(32, 8), 0, stream>>>(Wout, woutT, D, D);
    k_gemm<false><<<dim3(NQKV / 128, S / 128), 256, 0, stream>>>(xb, wqkvT, bqkv, qkvb, S, NQKV, D);
    k_rope<<<(S * 40 * 16) / 256, 256, 0, stream>>>(qkvb);
    k_attn<<<dim3(NH, 16), 512, 0, stream>>>(qkvb, ao);
    k_gemm<true><<<dim3(D / 128, S / 128), 256, 0, stream>>>(ao, woutT, bout, out, S, D, D);
}